// Round 1
// baseline (11.885 us; speedup 1.0000x reference)
//
#include <hip/hip_runtime.h>

// HungarianMatcher cost-block kernel.
// Shapes (fixed by the problem): bs=8, seq=32 -> n=256 samples; q=32 queries;
// ncls=4; V=num_valid=16 (derived host-side from out_size / (n*q)).
// Output: [n, q, V] f32 where
//   out[s,i,j] = 5*L1(pred_box[s,i], tgt_box[s,j])
//              - pred_logits[s,i, hand_type[s,j]]
//              - 2*GIoU(xyxy(pred_box[s,i]), xyxy(tgt_box[s,j]))

#define NQ   32
#define NCLS 4

__global__ __launch_bounds__(256) void matcher_cost_kernel(
    const float* __restrict__ pred_logits,  // [n, NQ, NCLS]
    const float* __restrict__ pred_boxes,   // [n, NQ, 4] cxcywh
    const float* __restrict__ tgt_boxes,    // [n, NQ, 4] cxcywh
    const int*   __restrict__ hand_type,    // [n, NQ]
    float* __restrict__ out,                // [n, NQ, V]
    int V, int total)
{
    int gid = blockIdx.x * blockDim.x + threadIdx.x;
    if (gid >= total) return;

    int j = gid % V;              // target index within sample (j < V <= NQ)
    int t = gid / V;              // = s*NQ + i
    int i = t % NQ;               // query index
    int s = t / NQ;               // sample index (b*seq + t)

    const float4 pb = *reinterpret_cast<const float4*>(pred_boxes + (size_t)(s * NQ + i) * 4);
    const float4 tb = *reinterpret_cast<const float4*>(tgt_boxes  + (size_t)(s * NQ + j) * 4);

    // L1 cdist in cxcywh space
    float l1 = fabsf(pb.x - tb.x) + fabsf(pb.y - tb.y)
             + fabsf(pb.z - tb.z) + fabsf(pb.w - tb.w);

    // class cost: gather logit at target's class
    int cls = hand_type[s * NQ + j];
    float logit = pred_logits[(size_t)(s * NQ + i) * NCLS + cls];

    // cxcywh -> xyxy
    float px1 = pb.x - 0.5f * pb.z, py1 = pb.y - 0.5f * pb.w;
    float px2 = pb.x + 0.5f * pb.z, py2 = pb.y + 0.5f * pb.w;
    float tx1 = tb.x - 0.5f * tb.z, ty1 = tb.y - 0.5f * tb.w;
    float tx2 = tb.x + 0.5f * tb.z, ty2 = tb.y + 0.5f * tb.w;

    float area1 = (px2 - px1) * (py2 - py1);
    float area2 = (tx2 - tx1) * (ty2 - ty1);

    // intersection
    float lx = fmaxf(px1, tx1), ly = fmaxf(py1, ty1);
    float rx = fminf(px2, tx2), ry = fminf(py2, ty2);
    float iw = fmaxf(rx - lx, 0.0f), ih = fmaxf(ry - ly, 0.0f);
    float inter = iw * ih;
    float uni = area1 + area2 - inter;
    float iou = inter / uni;

    // smallest enclosing box
    float ex1 = fminf(px1, tx1), ey1 = fminf(py1, ty1);
    float ex2 = fmaxf(px2, tx2), ey2 = fmaxf(py2, ty2);
    float ew = fmaxf(ex2 - ex1, 0.0f), eh = fmaxf(ey2 - ey1, 0.0f);
    float ae = ew * eh;
    float giou = iou - (ae - uni) / ae;

    // C = 5*l1 + 1*(-logit) + 2*(-giou)
    out[gid] = 5.0f * l1 - logit - 2.0f * giou;
}

extern "C" void kernel_launch(void* const* d_in, const int* in_sizes, int n_in,
                              void* d_out, int out_size, void* d_ws, size_t ws_size,
                              hipStream_t stream) {
    const float* pred_logits = (const float*)d_in[0];
    const float* pred_boxes  = (const float*)d_in[1];
    const float* tgt_boxes   = (const float*)d_in[2];
    const int*   hand_type   = (const int*)d_in[3];
    float* out = (float*)d_out;

    // n*NQ = hand_type element count; V = out_size / (n*NQ)
    const int nq_total = in_sizes[3];          // n * NQ = 8192
    const int V = out_size / nq_total;         // = 16

    const int total = out_size;                // n * NQ * V
    const int block = 256;
    const int grid = (total + block - 1) / block;

    matcher_cost_kernel<<<grid, block, 0, stream>>>(
        pred_logits, pred_boxes, tgt_boxes, hand_type, out, V, total);
}

// Round 2
// 9.437 us; speedup vs baseline: 1.2593x; 1.2593x over previous
//
#include <hip/hip_runtime.h>

// HungarianMatcher cost-block kernel, 4 outputs/thread (vectorized stores).
// Shapes: n=256 samples (bs*seq), q=32 queries, ncls=4, V=16 (derived).
// out[s,i,j] = 5*L1(pred_box[s,i], tgt_box[s,j])
//            - pred_logits[s,i, hand_type[s,j]]
//            - 2*GIoU(xyxy(pred_box[s,i]), xyxy(tgt_box[s,j]))

#define NQ   32
#define NCLS 4

__device__ __forceinline__ float cost_one(float4 pb, float4 tb, float logit) {
    float l1 = fabsf(pb.x - tb.x) + fabsf(pb.y - tb.y)
             + fabsf(pb.z - tb.z) + fabsf(pb.w - tb.w);

    float px1 = pb.x - 0.5f * pb.z, py1 = pb.y - 0.5f * pb.w;
    float px2 = pb.x + 0.5f * pb.z, py2 = pb.y + 0.5f * pb.w;
    float tx1 = tb.x - 0.5f * tb.z, ty1 = tb.y - 0.5f * tb.w;
    float tx2 = tb.x + 0.5f * tb.z, ty2 = tb.y + 0.5f * tb.w;

    float area1 = (px2 - px1) * (py2 - py1);
    float area2 = (tx2 - tx1) * (ty2 - ty1);

    float lx = fmaxf(px1, tx1), ly = fmaxf(py1, ty1);
    float rx = fminf(px2, tx2), ry = fminf(py2, ty2);
    float iw = fmaxf(rx - lx, 0.0f), ih = fmaxf(ry - ly, 0.0f);
    float inter = iw * ih;
    float uni = area1 + area2 - inter;
    float iou = inter / uni;

    float ex1 = fminf(px1, tx1), ey1 = fminf(py1, ty1);
    float ex2 = fmaxf(px2, tx2), ey2 = fmaxf(py2, ty2);
    float ew = fmaxf(ex2 - ex1, 0.0f), eh = fmaxf(ey2 - ey1, 0.0f);
    float ae = ew * eh;
    float giou = iou - (ae - uni) / ae;

    return 5.0f * l1 - logit - 2.0f * giou;
}

__global__ __launch_bounds__(256) void matcher_cost_kernel(
    const float* __restrict__ pred_logits,  // [n, NQ, NCLS]
    const float* __restrict__ pred_boxes,   // [n, NQ, 4] cxcywh
    const float* __restrict__ tgt_boxes,    // [n, NQ, 4] cxcywh
    const int*   __restrict__ hand_type,    // [n, NQ]
    float* __restrict__ out,                // [n, NQ, V]
    int Vq, int total_vec)                  // Vq = V/4; total_vec = total/4
{
    int gid = blockIdx.x * blockDim.x + threadIdx.x;
    if (gid >= total_vec) return;

    int j4 = gid % Vq;            // which group of 4 targets
    int t  = gid / Vq;            // = s*NQ + i
    int i  = t % NQ;
    int s  = t / NQ;
    int j0 = j4 * 4;

    const float4 pb = *reinterpret_cast<const float4*>(
        pred_boxes + (size_t)(s * NQ + i) * 4);

    // 4 consecutive target boxes (64 B contiguous) and their class ids (16 B)
    const float4* tbp = reinterpret_cast<const float4*>(
        tgt_boxes + (size_t)(s * NQ + j0) * 4);
    const int4 cls = *reinterpret_cast<const int4*>(hand_type + s * NQ + j0);

    const float* lrow = pred_logits + (size_t)(s * NQ + i) * NCLS;

    float4 r;
    r.x = cost_one(pb, tbp[0], lrow[cls.x]);
    r.y = cost_one(pb, tbp[1], lrow[cls.y]);
    r.z = cost_one(pb, tbp[2], lrow[cls.z]);
    r.w = cost_one(pb, tbp[3], lrow[cls.w]);

    *reinterpret_cast<float4*>(out + (size_t)gid * 4) = r;
}

extern "C" void kernel_launch(void* const* d_in, const int* in_sizes, int n_in,
                              void* d_out, int out_size, void* d_ws, size_t ws_size,
                              hipStream_t stream) {
    const float* pred_logits = (const float*)d_in[0];
    const float* pred_boxes  = (const float*)d_in[1];
    const float* tgt_boxes   = (const float*)d_in[2];
    const int*   hand_type   = (const int*)d_in[3];
    float* out = (float*)d_out;

    const int nq_total = in_sizes[3];          // n * NQ = 8192
    const int V = out_size / nq_total;         // = 16 (multiple of 4 by problem setup)

    const int total_vec = out_size / 4;
    const int block = 256;
    const int grid = (total_vec + block - 1) / block;

    matcher_cost_kernel<<<grid, block, 0, stream>>>(
        pred_logits, pred_boxes, tgt_boxes, hand_type, out, V / 4, total_vec);
}